// Round 5
// baseline (592.925 us; speedup 1.0000x reference)
//
#include <hip/hip_runtime.h>

// ---------------------------------------------------------------------------
// STEncoder (STGCN-style) on MI355X.
// B=16, N=2000 (pad 2048), T=12, D_IN=3, C=64, CM=32, KS=KT=3.
// GLU/theta/t2 convs are small-M GEMMs -> unified MFMA kernel k_mix with
// frag-packed LDS staging. Chebyshev: T0=I, T2=2L^2-I -> 2 big GEMMs/block.
// R5: k_mix<0> 64-col tiles (49.5KB LDS -> 3 blocks/CU) + batched staging
//     loads; k_gemm 256-thread blocks (10 waves/CU) with sigma-swizzle+dbuf.
// ---------------------------------------------------------------------------

typedef unsigned short u16;
typedef __attribute__((ext_vector_type(8))) short short8;   // 8 x bf16 frag
typedef __attribute__((ext_vector_type(4))) float floatx4;  // MFMA acc

struct __attribute__((aligned(8))) us4 { u16 v[4]; };

#define AS1 __attribute__((address_space(1)))
#define AS3 __attribute__((address_space(3)))

__device__ __forceinline__ float b2f(u16 h) {
  union { unsigned int u; float f; } v;
  v.u = ((unsigned int)h) << 16;
  return v.f;
}
__device__ __forceinline__ u16 f2b(float f) {
  union { float f; unsigned int u; } v;
  v.f = f;
  unsigned int r = (v.u + 0x7fffu + ((v.u >> 16) & 1u)) >> 16;
  return (u16)r;
}
__device__ __forceinline__ void gl_lds16(const u16* g, u16* l) {
  __builtin_amdgcn_global_load_lds((const AS1 unsigned int*)g,
                                   (AS3 unsigned int*)l, 16, 0, 0);
}
__device__ __forceinline__ us4 load4_guard(const u16* gp, int n) {
  if (n + 3 < 2000) return *(const us4*)gp;
  us4 r;
#pragma unroll
  for (int i = 0; i < 4; ++i) r.v[i] = (n + i < 2000) ? gp[i] : (u16)0;
  return r;
}

// --------------------------- graph preprocessing ---------------------------

__global__ void k_deg(const float* __restrict__ graph, float* __restrict__ d) {
  const int n = blockIdx.x;
  const int tid = threadIdx.x;
  float s = 0.f;
  const float* row = graph + (size_t)n * 2000;
  for (int m4 = tid; m4 < 500; m4 += 256) {
    const float4 g = *(const float4*)(row + m4 * 4);
    s += (g.x + g.y) + (g.z + g.w);
  }
  __shared__ float red[256];
  red[tid] = s;
  __syncthreads();
  for (int st = 128; st > 0; st >>= 1) {
    if (tid < st) red[tid] += red[tid + st];
    __syncthreads();
  }
  if (tid == 0) d[n] = rsqrtf(fmaxf(red[0] + 1.f, 1e-6f));
}

__global__ void k_lap(const float* __restrict__ graph, const float* __restrict__ d,
                      u16* __restrict__ L) {
  const int m = blockIdx.x * 1024 + threadIdx.x * 4;
  const int n = blockIdx.y;
  us4 r = {{0, 0, 0, 0}};
  if (n < 2000 && m < 2000) {
    const float4 g4 = *(const float4*)(graph + (size_t)n * 2000 + m);
    const float4 d4 = *(const float4*)(d + m);
    const float dn = d[n];
    const float gv[4] = {g4.x, g4.y, g4.z, g4.w};
    const float dv[4] = {d4.x, d4.y, d4.z, d4.w};
#pragma unroll
    for (int i = 0; i < 4; ++i) {
      const float delta = (n == m + i) ? 1.f : 0.f;
      r.v[i] = f2b(delta - dn * (gv[i] + delta) * dv[i]);
    }
  }
  *(us4*)(L + (size_t)n * 2048 + m) = r;
}

// --------------------------- input 1x1 conv (K=3) ---------------------------

__global__ void k_inconv(const float* __restrict__ x, const float* __restrict__ w,
                         const float* __restrict__ bias, u16* __restrict__ h0) {
  const int n = blockIdx.x * 1024 + threadIdx.x * 4;
  if (n >= 2000) return;
  const int b = blockIdx.y / 12, t = blockIdx.y % 12;
  const float4 x0 = *(const float4*)(x + ((size_t)(b * 3 + 0) * 12 + t) * 2000 + n);
  const float4 x1 = *(const float4*)(x + ((size_t)(b * 3 + 1) * 12 + t) * 2000 + n);
  const float4 x2 = *(const float4*)(x + ((size_t)(b * 3 + 2) * 12 + t) * 2000 + n);
  for (int o = 0; o < 64; ++o) {
    const float w0 = w[o], w1 = w[64 + o], w2 = w[128 + o], bb = bias[o];
    us4 r;
    r.v[0] = f2b(x0.x * w0 + x1.x * w1 + x2.x * w2 + bb);
    r.v[1] = f2b(x0.y * w0 + x1.y * w1 + x2.y * w2 + bb);
    r.v[2] = f2b(x0.z * w0 + x1.z * w1 + x2.z * w2 + bb);
    r.v[3] = f2b(x0.w * w0 + x1.w * w1 + x2.w * w2 + bb);
    *(us4*)(h0 + ((size_t)(b * 64 + o) * 12 + t) * 2000 + n) = r;
  }
}

// --------------------------- weight fragment packing ------------------------
__global__ void k_wpack(const float* __restrict__ t1w, const float* __restrict__ aw,
                        const float* __restrict__ th, const float* __restrict__ t2w,
                        u16* __restrict__ wglu, u16* __restrict__ wth,
                        u16* __restrict__ wt2) {
  const int mode = blockIdx.x;
  const int tid = threadIdx.x;
  if (mode == 0) {  // GLU: M=64, K=192, KS=6
    for (int idx = tid; idx < 1536 * 8; idx += 256) {
      int chunk = idx >> 3, j = idx & 7;
      int l15 = chunk & 15, quad = (chunk >> 4) & 3, g = chunk >> 6;
      int ks = g % 6, mi = g / 6;
      int o = mi * 16 + l15;
      int k = ks * 32 + quad * 8 + j;
      int c = k & 63, dt = k >> 6;
      float v = t1w[(o * 64 + c) * 3 + dt];
      if (o < 32 && dt == 2) v += aw[o * 64 + c];
      wglu[idx] = f2b(v);
    }
  } else if (mode == 1) {  // theta: M=32, K=96, KS=3 (padded to 512 chunks)
    for (int idx = tid; idx < 512 * 8; idx += 256) {
      int chunk = idx >> 3, j = idx & 7;
      int l15 = chunk & 15, quad = (chunk >> 4) & 3, g = chunk >> 6;
      float v = 0.f;
      if (g < 6) {
        int ks = g % 3, mi = g / 3;
        int o = mi * 16 + l15;
        int k = ks * 32 + quad * 8 + j;
        int i = k & 31, src = k >> 5;
        const float* p = th + (i * 32 + o) * 3;
        v = (src == 0) ? (p[0] - p[2]) : (src == 1 ? p[1] : 2.f * p[2]);
      }
      wth[idx] = f2b(v);
    }
  } else {  // t2: M=64, K=96, KS=3
    for (int idx = tid; idx < 768 * 8; idx += 256) {
      int chunk = idx >> 3, j = idx & 7;
      int l15 = chunk & 15, quad = (chunk >> 4) & 3, g = chunk >> 6;
      int ks = g % 3, mi = g / 3;
      int o = mi * 16 + l15;
      int k = ks * 32 + quad * 8 + j;
      int i = k & 31, dt = k >> 5;
      wt2[idx] = f2b(t2w[(o * 32 + i) * 3 + dt]);
    }
  }
}

// --------------------------- unified MFMA conv/mix kernel -------------------
// NT = n-tile cols (64 for GLU -> 49.5KB LDS -> 3 blocks/CU; 128 otherwise).
// Staging: 3 passes, ALL global loads issued before any ds_write (max MLP).
template <int MODE>
__global__ __launch_bounds__(256, 2)
void k_mix(const u16* __restrict__ x0, const u16* __restrict__ y1,
           const u16* __restrict__ y2, const u16* __restrict__ wp,
           const float* __restrict__ b0, const float* __restrict__ b1,
           u16* __restrict__ out, int T_in, int T) {
  constexpr int M = (MODE == 1) ? 32 : 64;
  constexpr int K = (MODE == 0) ? 192 : 96;
  constexpr int KS = K / 32;
  constexpr int MT = M / 16;
  constexpr int NT = (MODE == 0) ? 64 : 128;    // n-tile width
  constexpr int NBLK = NT / 16;
  constexpr int NJ = NBLK / 4;                  // n-frags per wave
  constexpr int TPR = NT / 4;                   // threads per row-group
  constexpr int GPP = 256 / TPR;                // row-groups per pass
  constexpr int WCH = ((MT * KS * 64) + 255) & ~255;
  constexpr int XCH = KS * NBLK * 65;
  __shared__ __align__(16) u16 lw[WCH * 8];
  __shared__ __align__(16) u16 lx[XCH * 8];

  const int tid = threadIdx.x;
  const int lane = tid & 63, wave = tid >> 6;
  const int quad = lane >> 4, l15 = lane & 15;
  const int n0 = blockIdx.x * NT;
  const int b = blockIdx.y / T, t = blockIdx.y % T;

#pragma unroll
  for (int p = 0; p < WCH / 256; ++p)
    gl_lds16(wp + (size_t)(p * 256 + wave * 64 + lane) * 8,
             &lw[(p * 256 + wave * 64) * 8]);

  const bool guard = (MODE != 1) && (n0 + NT > 2000);
  const int nloc = (tid % TPR) * 4;
  us4 rv[3][4];
#pragma unroll
  for (int p = 0; p < 3; ++p) {
    const int k4 = p * GPP + (tid / TPR);
#pragma unroll
    for (int i = 0; i < 4; ++i) {
      const int k = k4 * 4 + i;
      const u16* rp;
      if (MODE == 0) {
        rp = x0 + (size_t)((b * 64 + (k & 63)) * T_in + t + (k >> 6)) * 2000;
      } else if (MODE == 1) {
        const u16* base = (k < 32) ? x0 : ((k < 64) ? y1 : y2);
        rp = base + (size_t)((b * 32 + (k & 31)) * T_in + t) * 2048;
      } else {
        rp = x0 + (size_t)((b * 32 + (k & 31)) * T_in + t + (k >> 5)) * 2000;
      }
      rv[p][i] = guard ? load4_guard(rp + n0 + nloc, n0 + nloc)
                       : *(const us4*)(rp + n0 + nloc);
    }
  }
#pragma unroll
  for (int p = 0; p < 3; ++p) {
    const int k4 = p * GPP + (tid / TPR);
    const int ks = k4 >> 3, q8 = k4 & 7;
    const int quadw = (q8 >> 1) & 3;
    const int j0 = (q8 & 1) * 4;
#pragma unroll
    for (int i = 0; i < 4; ++i) {
      const int nn = nloc + i;
      const int chunk = (ks * NBLK + (nn >> 4)) * 65 + quadw * 16 + (nn & 15);
      us4 wv;
      wv.v[0] = rv[p][0].v[i]; wv.v[1] = rv[p][1].v[i];
      wv.v[2] = rv[p][2].v[i]; wv.v[3] = rv[p][3].v[i];
      *(us4*)&lx[chunk * 8 + j0] = wv;
    }
  }
  asm volatile("s_waitcnt vmcnt(0)" ::: "memory");
  __syncthreads();

  floatx4 acc[MT][NJ] = {};
#pragma unroll
  for (int ks = 0; ks < KS; ++ks) {
    short8 bfr[NJ], afr[MT];
#pragma unroll
    for (int nj = 0; nj < NJ; ++nj)
      bfr[nj] = *(const short8*)
          &lx[(((ks * NBLK + wave * NJ + nj) * 65) + lane) * 8];
#pragma unroll
    for (int mi = 0; mi < MT; ++mi)
      afr[mi] = *(const short8*)&lw[((mi * KS + ks) * 64 + lane) * 8];
#pragma unroll
    for (int mi = 0; mi < MT; ++mi)
#pragma unroll
      for (int nj = 0; nj < NJ; ++nj)
        acc[mi][nj] = __builtin_amdgcn_mfma_f32_16x16x32_bf16(
            afr[mi], bfr[nj], acc[mi][nj], 0, 0, 0);
  }

#pragma unroll
  for (int nj = 0; nj < NJ; ++nj) {
    const int nblk = wave * NJ + nj;
    const int n = n0 + nblk * 16 + l15;
    if (MODE == 0) {
#pragma unroll
      for (int mi = 0; mi < 2; ++mi)
#pragma unroll
        for (int r = 0; r < 4; ++r) {
          const int i = mi * 16 + quad * 4 + r;
          const float sv = acc[mi][nj][r] + b0[i] + b1[i];
          const float gt = acc[mi + 2][nj][r] + b0[32 + i];
          const float val = sv / (1.f + __expf(-gt));
          out[(size_t)((b * 32 + i) * T + t) * 2048 + n] = f2b(val);
        }
    } else if (MODE == 1) {
#pragma unroll
      for (int mi = 0; mi < MT; ++mi)
#pragma unroll
        for (int r = 0; r < 4; ++r) {
          const int o = mi * 16 + quad * 4 + r;
          const int rc = nblk * 65 + ((o >> 3) & 3) * 16 + l15;
          float v = acc[mi][nj][r] + b0[o] + b2f(lx[rc * 8 + (o & 7)]);
          if (n < 2000)
            out[(size_t)((b * 32 + o) * T + t) * 2000 + n] = f2b(fmaxf(v, 0.f));
        }
    } else {
#pragma unroll
      for (int mi = 0; mi < MT; ++mi)
#pragma unroll
        for (int r = 0; r < 4; ++r) {
          const int o = mi * 16 + quad * 4 + r;
          float v = acc[mi][nj][r] + b0[o];
          if (o < 32) {
            const int rc = (2 * NBLK + nblk) * 65 + ((o >> 3) & 3) * 16 + l15;
            v += b2f(lx[rc * 8 + (o & 7)]);
          }
          if (n < 2000)
            out[(size_t)((b * 64 + o) * T + t) * 2000 + n] = f2b(fmaxf(v, 0.f));
        }
    }
  }
}

// --------------------------- bf16 MFMA GEMM (C = A * Bt^T) ------------------
// 256 threads, block tile 128x128, 2x2 waves of 64x64 (16 MFMA / 8 reads).
// sigma-swizzled LDS (conflict-free b128 reads) + explicit double buffer:
// per K-step {vmcnt(own prev DMAs) ; s_barrier ; DMA next tile into other
// buffer ; ds_read ; MFMA}. 640-block grid x 4 waves = 10 waves/CU.
__global__ __launch_bounds__(256, 2)
void k_gemm(const u16* __restrict__ A, const u16* __restrict__ Bt,
            u16* __restrict__ C) {
  constexpr int K = 2048;
  __shared__ u16 As[2][128 * 32];
  __shared__ u16 Bs[2][128 * 32];
  const int tid = threadIdx.x;
  const int lane = tid & 63, wave = tid >> 6;
  const int m0 = blockIdx.y * 128, n0 = blockIdx.x * 128;
  const int wy = wave >> 1, wx = wave & 1;
  const int quad = lane >> 4, l15 = lane & 15;

  // staging chunks: c = instr-half*64 + wave*128 + lane; row=c>>2, pos=c&3,
  // global chunk q = (pos - sig(row&15)) & 3, sig(x)=(x+(x>>2))&3
  const int c0 = wave * 128 + lane;
  const int c1 = c0 + 64;
  const int r0 = c0 >> 2, r1 = c1 >> 2;
  const int q0 = (((c0 & 3) - ((r0 & 15) + ((r0 & 15) >> 2))) & 3);
  const int q1 = (((c1 & 3) - ((r1 & 15) + ((r1 & 15) >> 2))) & 3);
  const u16* Ag0 = A + (size_t)(m0 + r0) * K + q0 * 8;
  const u16* Ag1 = A + (size_t)(m0 + r1) * K + q1 * 8;
  const u16* Bg0 = Bt + (size_t)(n0 + r0) * K + q0 * 8;
  const u16* Bg1 = Bt + (size_t)(n0 + r1) * K + q1 * 8;
  const int lofs0 = (wave * 2 + 0) * 512;
  const int lofs1 = (wave * 2 + 1) * 512;

  // fragment read addresses (sigma-swizzled)
  const int sigr = (l15 + (l15 >> 2)) & 3;
  const int cofs = ((quad + sigr) & 3) * 8;

  floatx4 acc[4][4] = {};

  gl_lds16(Ag0, As[0] + lofs0);
  gl_lds16(Ag1, As[0] + lofs1);
  gl_lds16(Bg0, Bs[0] + lofs0);
  gl_lds16(Bg1, Bs[0] + lofs1);

  int cur = 0;
  for (int k0 = 0; k0 < K; k0 += 32) {
    asm volatile("s_waitcnt vmcnt(0)" ::: "memory");  // own prev-tile DMAs
    asm volatile("s_barrier" ::: "memory");
    if (k0 + 32 < K) {
      const int kn = k0 + 32;
      u16* ad = As[cur ^ 1];
      u16* bd = Bs[cur ^ 1];
      gl_lds16(Ag0 + kn, ad + lofs0);
      gl_lds16(Ag1 + kn, ad + lofs1);
      gl_lds16(Bg0 + kn, bd + lofs0);
      gl_lds16(Bg1 + kn, bd + lofs1);
    }
    const u16* as = As[cur];
    const u16* bs = Bs[cur];
    short8 af[4], bf[4];
#pragma unroll
    for (int mi = 0; mi < 4; ++mi)
      af[mi] = *(const short8*)&as[(wy * 64 + mi * 16 + l15) * 32 + cofs];
#pragma unroll
    for (int ni = 0; ni < 4; ++ni)
      bf[ni] = *(const short8*)&bs[(wx * 64 + ni * 16 + l15) * 32 + cofs];
#pragma unroll
    for (int mi = 0; mi < 4; ++mi)
#pragma unroll
      for (int ni = 0; ni < 4; ++ni)
        acc[mi][ni] = __builtin_amdgcn_mfma_f32_16x16x32_bf16(
            af[mi], bf[ni], acc[mi][ni], 0, 0, 0);
    cur ^= 1;
  }

#pragma unroll
  for (int mi = 0; mi < 4; ++mi) {
#pragma unroll
    for (int ni = 0; ni < 4; ++ni) {
      const int row = m0 + wy * 64 + mi * 16 + quad * 4;
      const int col = n0 + wx * 64 + ni * 16 + l15;
#pragma unroll
      for (int r = 0; r < 4; ++r)
        C[(size_t)(row + r) * K + col] = f2b(acc[mi][ni][r]);
    }
  }
}

// --------------------------- LayerNorm --------------------------------------

__global__ void k_lnpart(const u16* __restrict__ h, float* __restrict__ part, int T) {
  const int bt = blockIdx.x, cg = blockIdx.y;
  const int b = bt / T, t = bt % T;
  const int tid = threadIdx.x;
  float s = 0.f, ss = 0.f;
  for (int c = cg * 8; c < cg * 8 + 8; ++c) {
    const u16* row = h + (size_t)((b * 64 + c) * T + t) * 2000;
    for (int n = tid * 4; n < 2000; n += 1024) {
      const us4 hv = *(const us4*)(row + n);
#pragma unroll
      for (int i = 0; i < 4; ++i) {
        const float v = b2f(hv.v[i]);
        s += v; ss += v * v;
      }
    }
  }
  __shared__ float r1[256], r2[256];
  r1[tid] = s; r2[tid] = ss;
  __syncthreads();
  for (int st = 128; st > 0; st >>= 1) {
    if (tid < st) { r1[tid] += r1[tid + st]; r2[tid] += r2[tid + st]; }
    __syncthreads();
  }
  if (tid == 0) {
    part[(bt * 8 + cg) * 2 + 0] = r1[0];
    part[(bt * 8 + cg) * 2 + 1] = r2[0];
  }
}

__global__ void k_lnfin(const float* __restrict__ part, float* __restrict__ stats,
                        int BT) {
  const int i = blockIdx.x * 256 + threadIdx.x;
  if (i >= BT) return;
  float s = 0.f, ss = 0.f;
  for (int g = 0; g < 8; ++g) {
    s  += part[(i * 8 + g) * 2 + 0];
    ss += part[(i * 8 + g) * 2 + 1];
  }
  const float inv = 1.f / 128000.f;
  const float mu = s * inv;
  const float var = ss * inv - mu * mu;
  stats[i * 2] = mu;
  stats[i * 2 + 1] = rsqrtf(var + 1e-5f);
}

// transpose gamma/beta [2000,64] -> [64,2048] (pad zeros)
__global__ void k_lngbT(const float* __restrict__ gw, const float* __restrict__ gb,
                        float* __restrict__ gwT, float* __restrict__ gbT) {
  const int n = blockIdx.x * 256 + threadIdx.x;
  const int c = blockIdx.y;
  float vw = 0.f, vb = 0.f;
  if (n < 2000) {
    vw = gw[(size_t)n * 64 + c];
    vb = gb[(size_t)n * 64 + c];
  }
  gwT[(size_t)c * 2048 + n] = vw;
  gbT[(size_t)c * 2048 + n] = vb;
}

__global__ void k_lnapply(u16* __restrict__ h, const float* __restrict__ stats,
                          const float* __restrict__ gwT, const float* __restrict__ gbT,
                          float* __restrict__ outf, int T, int write_f32) {
  const int n = blockIdx.x * 1024 + threadIdx.x * 4;
  if (n >= 2000) return;
  int by = blockIdx.y;
  const int t = by % T; by /= T;
  const int c = by & 63;
  const int b = by >> 6;
  const int bt = b * T + t;
  const float mu = stats[bt * 2], rs = stats[bt * 2 + 1];
  const size_t row = (size_t)((b * 64 + c) * T + t) * 2000 + n;
  const us4 hv = *(const us4*)(h + row);
  const float4 w4 = *(const float4*)(gwT + (size_t)c * 2048 + n);
  const float4 b4 = *(const float4*)(gbT + (size_t)c * 2048 + n);
  const float o0 = (b2f(hv.v[0]) - mu) * rs * w4.x + b4.x;
  const float o1 = (b2f(hv.v[1]) - mu) * rs * w4.y + b4.y;
  const float o2 = (b2f(hv.v[2]) - mu) * rs * w4.z + b4.z;
  const float o3 = (b2f(hv.v[3]) - mu) * rs * w4.w + b4.w;
  if (write_f32) {
    *(float4*)(outf + row) = make_float4(o0, o1, o2, o3);
  } else {
    us4 r;
    r.v[0] = f2b(o0); r.v[1] = f2b(o1); r.v[2] = f2b(o2); r.v[3] = f2b(o3);
    *(us4*)(h + row) = r;
  }
}

// --------------------------- launch -----------------------------------------

extern "C" void kernel_launch(void* const* d_in, const int* in_sizes, int n_in,
                              void* d_out, int out_size, void* d_ws, size_t ws_size,
                              hipStream_t stream) {
  const float* x     = (const float*)d_in[0];
  const float* graph = (const float*)d_in[1];
  const float* in_w  = (const float*)d_in[2];
  const float* in_b  = (const float*)d_in[3];

  char* ws = (char*)d_ws;
  size_t off = 0;
  auto alloc = [&](size_t bytes) -> void* {
    void* p = ws + off;
    off += (bytes + 255) & ~(size_t)255;
    return p;
  };
  float* dd    = (float*)alloc(2048 * 4);
  float* stats = (float*)alloc(16 * 12 * 2 * 4);
  float* part  = (float*)alloc(16 * 8 * 8 * 2 * 4);
  float* gwT   = (float*)alloc((size_t)64 * 2048 * 4);
  float* gbT   = (float*)alloc((size_t)64 * 2048 * 4);
  u16* wpg  = (u16*)alloc((size_t)1536 * 8 * 2);
  u16* wpt  = (u16*)alloc((size_t)512 * 8 * 2);
  u16* wp2  = (u16*)alloc((size_t)768 * 8 * 2);
  u16* L    = (u16*)alloc((size_t)2048 * 2048 * 2);
  u16* h0   = (u16*)alloc((size_t)16 * 64 * 12 * 2000 * 2);
  u16* Xp   = (u16*)alloc((size_t)5120 * 2048 * 2);
  u16* Y1   = (u16*)alloc((size_t)5120 * 2048 * 2);
  u16* Y2   = (u16*)alloc((size_t)5120 * 2048 * 2);
  u16* sbuf = (u16*)alloc((size_t)16 * 32 * 10 * 2000 * 2);
  u16* h1   = (u16*)alloc((size_t)16 * 64 * 8 * 2000 * 2);
  u16* h2   = h0;  // reuse: h0 dead after block-1 GLU
  if (off > ws_size) return;

  k_deg<<<dim3(2000), dim3(256), 0, stream>>>(graph, dd);
  k_lap<<<dim3(2, 2048), dim3(256), 0, stream>>>(graph, dd, L);
  k_inconv<<<dim3(2, 192), dim3(256), 0, stream>>>(x, in_w, in_b, h0);

  for (int blk = 0; blk < 2; ++blk) {
    const int base = 4 + blk * 10;
    const float* t1w = (const float*)d_in[base + 0];
    const float* t1b = (const float*)d_in[base + 1];
    const float* aw  = (const float*)d_in[base + 2];
    const float* ab  = (const float*)d_in[base + 3];
    const float* th  = (const float*)d_in[base + 4];
    const float* sb  = (const float*)d_in[base + 5];
    const float* t2w = (const float*)d_in[base + 6];
    const float* t2b = (const float*)d_in[base + 7];
    const float* lng = (const float*)d_in[base + 8];
    const float* lnb = (const float*)d_in[base + 9];

    const int T_in = (blk == 0) ? 12 : 8;
    const int T_g  = T_in - 2;  // 10 / 6
    const int T_o  = T_g - 2;   // 8 / 4
    const u16* hin = (blk == 0) ? h0 : h1;
    u16* hout      = (blk == 0) ? h1 : h2;
    const int M = 16 * 32 * T_g;  // 5120 / 3072

    k_wpack<<<dim3(3), dim3(256), 0, stream>>>(t1w, aw, th, t2w, wpg, wpt, wp2);
    k_lngbT<<<dim3(8, 64), dim3(256), 0, stream>>>(lng, lnb, gwT, gbT);
    k_mix<0><<<dim3(32, 16 * T_g), dim3(256), 0, stream>>>(
        hin, nullptr, nullptr, wpg, t1b, ab, Xp, T_in, T_g);
    k_gemm<<<dim3(16, M / 128), dim3(256), 0, stream>>>(Xp, L, Y1);
    k_gemm<<<dim3(16, M / 128), dim3(256), 0, stream>>>(Y1, L, Y2);
    k_mix<1><<<dim3(16, 16 * T_g), dim3(256), 0, stream>>>(
        Xp, Y1, Y2, wpt, sb, nullptr, sbuf, T_g, T_g);
    k_mix<2><<<dim3(16, 16 * T_o), dim3(256), 0, stream>>>(
        sbuf, nullptr, nullptr, wp2, t2b, nullptr, hout, T_g, T_o);
    k_lnpart<<<dim3(16 * T_o, 8), dim3(256), 0, stream>>>(hout, part, T_o);
    k_lnfin<<<dim3(1), dim3(256), 0, stream>>>(part, stats, 16 * T_o);
    k_lnapply<<<dim3(2, 16 * 64 * T_o), dim3(256), 0, stream>>>(
        hout, stats, gwT, gbT, (float*)d_out, T_o, blk);
  }
}

// Round 6
// 559.533 us; speedup vs baseline: 1.0597x; 1.0597x over previous
//
#include <hip/hip_runtime.h>

// ---------------------------------------------------------------------------
// STEncoder (STGCN-style) on MI355X.
// B=16, N=2000 (pad 2048), T=12, D_IN=3, C=64, CM=32, KS=KT=3.
// Chebyshev: T0=I, T2=2L^2-I -> 2 big GEMMs/block, k0/k2 folded into theta.
// R6: k_gemm __launch_bounds__(256,4) -> whole grid co-resident (no tail,
//     16 waves/CU); fused k_mix12 = theta+t2 in one kernel (theta-out kept
//     in LDS in t2 B-frag layout; sbuf round-trip eliminated).
// ---------------------------------------------------------------------------

typedef unsigned short u16;
typedef __attribute__((ext_vector_type(8))) short short8;   // 8 x bf16 frag
typedef __attribute__((ext_vector_type(4))) float floatx4;  // MFMA acc

struct __attribute__((aligned(8))) us4 { u16 v[4]; };

#define AS1 __attribute__((address_space(1)))
#define AS3 __attribute__((address_space(3)))

__device__ __forceinline__ float b2f(u16 h) {
  union { unsigned int u; float f; } v;
  v.u = ((unsigned int)h) << 16;
  return v.f;
}
__device__ __forceinline__ u16 f2b(float f) {
  union { float f; unsigned int u; } v;
  v.f = f;
  unsigned int r = (v.u + 0x7fffu + ((v.u >> 16) & 1u)) >> 16;
  return (u16)r;
}
__device__ __forceinline__ void gl_lds16(const u16* g, u16* l) {
  __builtin_amdgcn_global_load_lds((const AS1 unsigned int*)g,
                                   (AS3 unsigned int*)l, 16, 0, 0);
}
__device__ __forceinline__ us4 load4_guard(const u16* gp, int n) {
  if (n + 3 < 2000) return *(const us4*)gp;
  us4 r;
#pragma unroll
  for (int i = 0; i < 4; ++i) r.v[i] = (n + i < 2000) ? gp[i] : (u16)0;
  return r;
}

// --------------------------- graph preprocessing ---------------------------

__global__ void k_deg(const float* __restrict__ graph, float* __restrict__ d) {
  const int n = blockIdx.x;
  const int tid = threadIdx.x;
  float s = 0.f;
  const float* row = graph + (size_t)n * 2000;
  for (int m4 = tid; m4 < 500; m4 += 256) {
    const float4 g = *(const float4*)(row + m4 * 4);
    s += (g.x + g.y) + (g.z + g.w);
  }
  __shared__ float red[256];
  red[tid] = s;
  __syncthreads();
  for (int st = 128; st > 0; st >>= 1) {
    if (tid < st) red[tid] += red[tid + st];
    __syncthreads();
  }
  if (tid == 0) d[n] = rsqrtf(fmaxf(red[0] + 1.f, 1e-6f));
}

__global__ void k_lap(const float* __restrict__ graph, const float* __restrict__ d,
                      u16* __restrict__ L) {
  const int m = blockIdx.x * 1024 + threadIdx.x * 4;
  const int n = blockIdx.y;
  us4 r = {{0, 0, 0, 0}};
  if (n < 2000 && m < 2000) {
    const float4 g4 = *(const float4*)(graph + (size_t)n * 2000 + m);
    const float4 d4 = *(const float4*)(d + m);
    const float dn = d[n];
    const float gv[4] = {g4.x, g4.y, g4.z, g4.w};
    const float dv[4] = {d4.x, d4.y, d4.z, d4.w};
#pragma unroll
    for (int i = 0; i < 4; ++i) {
      const float delta = (n == m + i) ? 1.f : 0.f;
      r.v[i] = f2b(delta - dn * (gv[i] + delta) * dv[i]);
    }
  }
  *(us4*)(L + (size_t)n * 2048 + m) = r;
}

// --------------------------- input 1x1 conv (K=3) ---------------------------

__global__ void k_inconv(const float* __restrict__ x, const float* __restrict__ w,
                         const float* __restrict__ bias, u16* __restrict__ h0) {
  const int n = blockIdx.x * 1024 + threadIdx.x * 4;
  if (n >= 2000) return;
  const int b = blockIdx.y / 12, t = blockIdx.y % 12;
  const float4 x0 = *(const float4*)(x + ((size_t)(b * 3 + 0) * 12 + t) * 2000 + n);
  const float4 x1 = *(const float4*)(x + ((size_t)(b * 3 + 1) * 12 + t) * 2000 + n);
  const float4 x2 = *(const float4*)(x + ((size_t)(b * 3 + 2) * 12 + t) * 2000 + n);
  for (int o = 0; o < 64; ++o) {
    const float w0 = w[o], w1 = w[64 + o], w2 = w[128 + o], bb = bias[o];
    us4 r;
    r.v[0] = f2b(x0.x * w0 + x1.x * w1 + x2.x * w2 + bb);
    r.v[1] = f2b(x0.y * w0 + x1.y * w1 + x2.y * w2 + bb);
    r.v[2] = f2b(x0.z * w0 + x1.z * w1 + x2.z * w2 + bb);
    r.v[3] = f2b(x0.w * w0 + x1.w * w1 + x2.w * w2 + bb);
    *(us4*)(h0 + ((size_t)(b * 64 + o) * 12 + t) * 2000 + n) = r;
  }
}

// --------------------------- weight fragment packing ------------------------
__global__ void k_wpack(const float* __restrict__ t1w, const float* __restrict__ aw,
                        const float* __restrict__ th, const float* __restrict__ t2w,
                        u16* __restrict__ wglu, u16* __restrict__ wth,
                        u16* __restrict__ wt2) {
  const int mode = blockIdx.x;
  const int tid = threadIdx.x;
  if (mode == 0) {  // GLU: M=64, K=192, KS=6
    for (int idx = tid; idx < 1536 * 8; idx += 256) {
      int chunk = idx >> 3, j = idx & 7;
      int l15 = chunk & 15, quad = (chunk >> 4) & 3, g = chunk >> 6;
      int ks = g % 6, mi = g / 6;
      int o = mi * 16 + l15;
      int k = ks * 32 + quad * 8 + j;
      int c = k & 63, dt = k >> 6;
      float v = t1w[(o * 64 + c) * 3 + dt];
      if (o < 32 && dt == 2) v += aw[o * 64 + c];
      wglu[idx] = f2b(v);
    }
  } else if (mode == 1) {  // theta: M=32, K=96, KS=3 (padded to 512 chunks)
    for (int idx = tid; idx < 512 * 8; idx += 256) {
      int chunk = idx >> 3, j = idx & 7;
      int l15 = chunk & 15, quad = (chunk >> 4) & 3, g = chunk >> 6;
      float v = 0.f;
      if (g < 6) {
        int ks = g % 3, mi = g / 3;
        int o = mi * 16 + l15;
        int k = ks * 32 + quad * 8 + j;
        int i = k & 31, src = k >> 5;
        const float* p = th + (i * 32 + o) * 3;
        v = (src == 0) ? (p[0] - p[2]) : (src == 1 ? p[1] : 2.f * p[2]);
      }
      wth[idx] = f2b(v);
    }
  } else {  // t2: M=64, K=96, KS=3
    for (int idx = tid; idx < 768 * 8; idx += 256) {
      int chunk = idx >> 3, j = idx & 7;
      int l15 = chunk & 15, quad = (chunk >> 4) & 3, g = chunk >> 6;
      int ks = g % 3, mi = g / 3;
      int o = mi * 16 + l15;
      int k = ks * 32 + quad * 8 + j;
      int i = k & 31, dt = k >> 5;
      wt2[idx] = f2b(t2w[(o * 32 + i) * 3 + dt]);
    }
  }
}

// --------------------------- GLU MFMA kernel (mode 0 only) ------------------
template <int MODE>
__global__ __launch_bounds__(256, 3)
void k_mix(const u16* __restrict__ x0, const u16* __restrict__ wp,
           const float* __restrict__ b0, const float* __restrict__ b1,
           u16* __restrict__ out, int T_in, int T) {
  constexpr int K = 192;
  constexpr int KS = K / 32;
  constexpr int MT = 4;
  constexpr int NT = 64;
  constexpr int NBLK = NT / 16;
  constexpr int TPR = NT / 4;
  constexpr int GPP = 256 / TPR;
  constexpr int WCH = ((MT * KS * 64) + 255) & ~255;
  constexpr int XCH = KS * NBLK * 65;
  __shared__ __align__(16) u16 lw[WCH * 8];
  __shared__ __align__(16) u16 lx[XCH * 8];

  const int tid = threadIdx.x;
  const int lane = tid & 63, wave = tid >> 6;
  const int quad = lane >> 4, l15 = lane & 15;
  const int n0 = blockIdx.x * NT;
  const int b = blockIdx.y / T, t = blockIdx.y % T;

#pragma unroll
  for (int p = 0; p < WCH / 256; ++p)
    gl_lds16(wp + (size_t)(p * 256 + wave * 64 + lane) * 8,
             &lw[(p * 256 + wave * 64) * 8]);

  const bool guard = (n0 + NT > 2000);
  const int nloc = (tid % TPR) * 4;
  us4 rv[3][4];
#pragma unroll
  for (int p = 0; p < 3; ++p) {
    const int k4 = p * GPP + (tid / TPR);
#pragma unroll
    for (int i = 0; i < 4; ++i) {
      const int k = k4 * 4 + i;
      const u16* rp =
          x0 + (size_t)((b * 64 + (k & 63)) * T_in + t + (k >> 6)) * 2000;
      rv[p][i] = guard ? load4_guard(rp + n0 + nloc, n0 + nloc)
                       : *(const us4*)(rp + n0 + nloc);
    }
  }
#pragma unroll
  for (int p = 0; p < 3; ++p) {
    const int k4 = p * GPP + (tid / TPR);
    const int ks = k4 >> 3, q8 = k4 & 7;
    const int quadw = (q8 >> 1) & 3;
    const int j0 = (q8 & 1) * 4;
#pragma unroll
    for (int i = 0; i < 4; ++i) {
      const int nn = nloc + i;
      const int chunk = (ks * NBLK + (nn >> 4)) * 65 + quadw * 16 + (nn & 15);
      us4 wv;
      wv.v[0] = rv[p][0].v[i]; wv.v[1] = rv[p][1].v[i];
      wv.v[2] = rv[p][2].v[i]; wv.v[3] = rv[p][3].v[i];
      *(us4*)&lx[chunk * 8 + j0] = wv;
    }
  }
  asm volatile("s_waitcnt vmcnt(0)" ::: "memory");
  __syncthreads();

  floatx4 acc[MT] = {};
#pragma unroll
  for (int ks = 0; ks < KS; ++ks) {
    short8 bfr = *(const short8*)&lx[(((ks * NBLK + wave) * 65) + lane) * 8];
#pragma unroll
    for (int mi = 0; mi < MT; ++mi) {
      short8 afr = *(const short8*)&lw[((mi * KS + ks) * 64 + lane) * 8];
      acc[mi] = __builtin_amdgcn_mfma_f32_16x16x32_bf16(afr, bfr, acc[mi], 0, 0, 0);
    }
  }

  const int n = n0 + wave * 16 + l15;
#pragma unroll
  for (int mi = 0; mi < 2; ++mi)
#pragma unroll
    for (int r = 0; r < 4; ++r) {
      const int i = mi * 16 + quad * 4 + r;
      const float sv = acc[mi][r] + b0[i] + b1[i];
      const float gt = acc[mi + 2][r] + b0[32 + i];
      const float val = sv / (1.f + __expf(-gt));
      out[(size_t)((b * 32 + i) * T + t) * 2048 + n] = f2b(val);
    }
}

// --------------------------- fused theta + t2 kernel ------------------------
// One block = one (b, 64-col n-slice), loops all t.
// Phase 1 (per t): stage X/Y1/Y2 (96x64) frag-packed; theta-MFMA (6 MFMA);
//   epilogue relu -> write theta-out INTO LDS in t2 B-frag layout (lt).
// Phase 2 (per t_o): t2-MFMA (12 MFMA) from lt; +bias +resid(theta[t_o+2]);
//   relu -> hout.
__global__ __launch_bounds__(256, 2)
void k_mix12(const u16* __restrict__ x0, const u16* __restrict__ y1,
             const u16* __restrict__ y2, const u16* __restrict__ wth,
             const u16* __restrict__ wt2, const float* __restrict__ sb,
             const float* __restrict__ t2b, u16* __restrict__ out,
             int T_g, int T_o) {
  __shared__ __align__(16) u16 lw1[512 * 8];        //  8 KB theta A-frags
  __shared__ __align__(16) u16 lw2[768 * 8];        // 12 KB t2 A-frags
  __shared__ __align__(16) u16 lx[780 * 8];         // 12 KB staging (96x64)
  __shared__ __align__(16) u16 lt[10 * 260 * 8];    // 41 KB theta-out ring

  const int tid = threadIdx.x;
  const int lane = tid & 63, wave = tid >> 6;
  const int quad = lane >> 4, l15 = lane & 15;
  const int n0 = blockIdx.x * 64;
  const int b = blockIdx.y;
  const int n = n0 + wave * 16 + l15;

#pragma unroll
  for (int p = 0; p < 2; ++p)
    gl_lds16(wth + (size_t)(p * 256 + wave * 64 + lane) * 8,
             &lw1[(p * 256 + wave * 64) * 8]);
#pragma unroll
  for (int p = 0; p < 3; ++p)
    gl_lds16(wt2 + (size_t)(p * 256 + wave * 64 + lane) * 8,
             &lw2[(p * 256 + wave * 64) * 8]);

  const int nloc = (tid & 15) * 4;      // TPR=16
  const int g16 = tid >> 4;             // 0..15 row-groups per pass

  for (int t = 0; t < T_g; ++t) {
    __syncthreads();  // lx free (prev theta done), lw DMAs drained (1st iter)
    us4 rv[2][4];
#pragma unroll
    for (int p = 0; p < 2; ++p) {
      const int k4 = p * 16 + g16;
      if (k4 < 24) {
#pragma unroll
        for (int i = 0; i < 4; ++i) {
          const int k = k4 * 4 + i;
          const u16* base = (k < 32) ? x0 : ((k < 64) ? y1 : y2);
          rv[p][i] = *(const us4*)(base +
              (size_t)((b * 32 + (k & 31)) * T_g + t) * 2048 + n0 + nloc);
        }
      }
    }
#pragma unroll
    for (int p = 0; p < 2; ++p) {
      const int k4 = p * 16 + g16;
      if (k4 < 24) {
        const int ks = k4 >> 3, q8 = k4 & 7;
        const int quadw = (q8 >> 1) & 3;
        const int j0 = (q8 & 1) * 4;
#pragma unroll
        for (int i = 0; i < 4; ++i) {
          const int nn = nloc + i;
          const int chunk = (ks * 4 + (nn >> 4)) * 65 + quadw * 16 + (nn & 15);
          us4 wv;
          wv.v[0] = rv[p][0].v[i]; wv.v[1] = rv[p][1].v[i];
          wv.v[2] = rv[p][2].v[i]; wv.v[3] = rv[p][3].v[i];
          *(us4*)&lx[chunk * 8 + j0] = wv;
        }
      }
    }
    __syncthreads();

    floatx4 acc[2] = {};
#pragma unroll
    for (int ks = 0; ks < 3; ++ks) {
      short8 bfr = *(const short8*)&lx[((ks * 4 + wave) * 65 + lane) * 8];
#pragma unroll
      for (int mi = 0; mi < 2; ++mi) {
        short8 afr = *(const short8*)&lw1[((mi * 3 + ks) * 64 + lane) * 8];
        acc[mi] = __builtin_amdgcn_mfma_f32_16x16x32_bf16(afr, bfr, acc[mi], 0, 0, 0);
      }
    }
    // epilogue: relu(acc + sb + X-resid) -> lt[t] in t2 B-frag layout
#pragma unroll
    for (int mi = 0; mi < 2; ++mi)
#pragma unroll
      for (int r = 0; r < 4; ++r) {
        const int o = mi * 16 + quad * 4 + r;
        const float v = acc[mi][r] + sb[o] +
            b2f(lx[(wave * 65 + ((o >> 3) & 3) * 16 + l15) * 8 + (o & 7)]);
        lt[((t * 4 + wave) * 65 + ((o >> 3) & 3) * 16 + l15) * 8 + (o & 7)] =
            f2b(fmaxf(v, 0.f));
      }
  }
  __syncthreads();

  for (int to = 0; to < T_o; ++to) {
    floatx4 acc[4] = {};
#pragma unroll
    for (int ks = 0; ks < 3; ++ks) {
      short8 bfr = *(const short8*)&lt[(((to + ks) * 4 + wave) * 65 + lane) * 8];
#pragma unroll
      for (int mi = 0; mi < 4; ++mi) {
        short8 afr = *(const short8*)&lw2[((mi * 3 + ks) * 64 + lane) * 8];
        acc[mi] = __builtin_amdgcn_mfma_f32_16x16x32_bf16(afr, bfr, acc[mi], 0, 0, 0);
      }
    }
    if (n < 2000) {
#pragma unroll
      for (int mi = 0; mi < 4; ++mi)
#pragma unroll
        for (int r = 0; r < 4; ++r) {
          const int o = mi * 16 + quad * 4 + r;
          float v = acc[mi][r] + t2b[o];
          if (o < 32)
            v += b2f(lt[(((to + 2) * 4 + wave) * 65 +
                         ((o >> 3) & 3) * 16 + l15) * 8 + (o & 7)]);
          out[(size_t)((b * 64 + o) * T_o + to) * 2000 + n] = f2b(fmaxf(v, 0.f));
        }
    }
  }
}

// --------------------------- bf16 MFMA GEMM (C = A * Bt^T) ------------------
// 256 threads, block tile 128x128, 2x2 waves of 64x64; sigma-swizzled LDS +
// explicit double buffer. R6: launch_bounds(256,4) -> 4 blocks/CU, entire
// grid (<=640 blocks) co-resident: no scheduling tail, 16 waves/CU.
__global__ __launch_bounds__(256, 4)
void k_gemm(const u16* __restrict__ A, const u16* __restrict__ Bt,
            u16* __restrict__ C) {
  constexpr int K = 2048;
  __shared__ u16 As[2][128 * 32];
  __shared__ u16 Bs[2][128 * 32];
  const int tid = threadIdx.x;
  const int lane = tid & 63, wave = tid >> 6;
  const int m0 = blockIdx.y * 128, n0 = blockIdx.x * 128;
  const int wy = wave >> 1, wx = wave & 1;
  const int quad = lane >> 4, l15 = lane & 15;

  const int c0 = wave * 128 + lane;
  const int c1 = c0 + 64;
  const int r0 = c0 >> 2, r1 = c1 >> 2;
  const int q0 = (((c0 & 3) - ((r0 & 15) + ((r0 & 15) >> 2))) & 3);
  const int q1 = (((c1 & 3) - ((r1 & 15) + ((r1 & 15) >> 2))) & 3);
  const u16* Ag0 = A + (size_t)(m0 + r0) * K + q0 * 8;
  const u16* Ag1 = A + (size_t)(m0 + r1) * K + q1 * 8;
  const u16* Bg0 = Bt + (size_t)(n0 + r0) * K + q0 * 8;
  const u16* Bg1 = Bt + (size_t)(n0 + r1) * K + q1 * 8;
  const int lofs0 = (wave * 2 + 0) * 512;
  const int lofs1 = (wave * 2 + 1) * 512;

  const int sigr = (l15 + (l15 >> 2)) & 3;
  const int cofs = ((quad + sigr) & 3) * 8;

  floatx4 acc[4][4] = {};

  gl_lds16(Ag0, As[0] + lofs0);
  gl_lds16(Ag1, As[0] + lofs1);
  gl_lds16(Bg0, Bs[0] + lofs0);
  gl_lds16(Bg1, Bs[0] + lofs1);

  int cur = 0;
  for (int k0 = 0; k0 < K; k0 += 32) {
    asm volatile("s_waitcnt vmcnt(0)" ::: "memory");
    asm volatile("s_barrier" ::: "memory");
    if (k0 + 32 < K) {
      const int kn = k0 + 32;
      u16* ad = As[cur ^ 1];
      u16* bd = Bs[cur ^ 1];
      gl_lds16(Ag0 + kn, ad + lofs0);
      gl_lds16(Ag1 + kn, ad + lofs1);
      gl_lds16(Bg0 + kn, bd + lofs0);
      gl_lds16(Bg1 + kn, bd + lofs1);
    }
    const u16* as = As[cur];
    const u16* bs = Bs[cur];
    short8 af[4], bf[4];
#pragma unroll
    for (int mi = 0; mi < 4; ++mi)
      af[mi] = *(const short8*)&as[(wy * 64 + mi * 16 + l15) * 32 + cofs];
#pragma unroll
    for (int ni = 0; ni < 4; ++ni)
      bf[ni] = *(const short8*)&bs[(wx * 64 + ni * 16 + l15) * 32 + cofs];
#pragma unroll
    for (int mi = 0; mi < 4; ++mi)
#pragma unroll
      for (int ni = 0; ni < 4; ++ni)
        acc[mi][ni] = __builtin_amdgcn_mfma_f32_16x16x32_bf16(
            af[mi], bf[ni], acc[mi][ni], 0, 0, 0);
    cur ^= 1;
  }

#pragma unroll
  for (int mi = 0; mi < 4; ++mi) {
#pragma unroll
    for (int ni = 0; ni < 4; ++ni) {
      const int row = m0 + wy * 64 + mi * 16 + quad * 4;
      const int col = n0 + wx * 64 + ni * 16 + l15;
#pragma unroll
      for (int r = 0; r < 4; ++r)
        C[(size_t)(row + r) * K + col] = f2b(acc[mi][ni][r]);
    }
  }
}

// --------------------------- LayerNorm --------------------------------------

__global__ void k_lnpart(const u16* __restrict__ h, float* __restrict__ part, int T) {
  const int bt = blockIdx.x, cg = blockIdx.y;
  const int b = bt / T, t = bt % T;
  const int tid = threadIdx.x;
  float s = 0.f, ss = 0.f;
  for (int c = cg * 8; c < cg * 8 + 8; ++c) {
    const u16* row = h + (size_t)((b * 64 + c) * T + t) * 2000;
    for (int n = tid * 4; n < 2000; n += 1024) {
      const us4 hv = *(const us4*)(row + n);
#pragma unroll
      for (int i = 0; i < 4; ++i) {
        const float v = b2f(hv.v[i]);
        s += v; ss += v * v;
      }
    }
  }
  __shared__ float r1[256], r2[256];
  r1[tid] = s; r2[tid] = ss;
  __syncthreads();
  for (int st = 128; st > 0; st >>= 1) {
    if (tid < st) { r1[tid] += r1[tid + st]; r2[tid] += r2[tid + st]; }
    __syncthreads();
  }
  if (tid == 0) {
    part[(bt * 8 + cg) * 2 + 0] = r1[0];
    part[(bt * 8 + cg) * 2 + 1] = r2[0];
  }
}

__global__ void k_lnfin(const float* __restrict__ part, float* __restrict__ stats,
                        int BT) {
  const int i = blockIdx.x * 256 + threadIdx.x;
  if (i >= BT) return;
  float s = 0.f, ss = 0.f;
  for (int g = 0; g < 8; ++g) {
    s  += part[(i * 8 + g) * 2 + 0];
    ss += part[(i * 8 + g) * 2 + 1];
  }
  const float inv = 1.f / 128000.f;
  const float mu = s * inv;
  const float var = ss * inv - mu * mu;
  stats[i * 2] = mu;
  stats[i * 2 + 1] = rsqrtf(var + 1e-5f);
}

// transpose gamma/beta [2000,64] -> [64,2048] (pad zeros)
__global__ void k_lngbT(const float* __restrict__ gw, const float* __restrict__ gb,
                        float* __restrict__ gwT, float* __restrict__ gbT) {
  const int n = blockIdx.x * 256 + threadIdx.x;
  const int c = blockIdx.y;
  float vw = 0.f, vb = 0.f;
  if (n < 2000) {
    vw = gw[(size_t)n * 64 + c];
    vb = gb[(size_t)n * 64 + c];
  }
  gwT[(size_t)c * 2048 + n] = vw;
  gbT[(size_t)c * 2048 + n] = vb;
}

__global__ void k_lnapply(u16* __restrict__ h, const float* __restrict__ stats,
                          const float* __restrict__ gwT, const float* __restrict__ gbT,
                          float* __restrict__ outf, int T, int write_f32) {
  const int n = blockIdx.x * 1024 + threadIdx.x * 4;
  if (n >= 2000) return;
  int by = blockIdx.y;
  const int t = by % T; by /= T;
  const int c = by & 63;
  const int b = by >> 6;
  const int bt = b * T + t;
  const float mu = stats[bt * 2], rs = stats[bt * 2 + 1];
  const size_t row = (size_t)((b * 64 + c) * T + t) * 2000 + n;
  const us4 hv = *(const us4*)(h + row);
  const float4 w4 = *(const float4*)(gwT + (size_t)c * 2048 + n);
  const float4 b4 = *(const float4*)(gbT + (size_t)c * 2048 + n);
  const float o0 = (b2f(hv.v[0]) - mu) * rs * w4.x + b4.x;
  const float o1 = (b2f(hv.v[1]) - mu) * rs * w4.y + b4.y;
  const float o2 = (b2f(hv.v[2]) - mu) * rs * w4.z + b4.z;
  const float o3 = (b2f(hv.v[3]) - mu) * rs * w4.w + b4.w;
  if (write_f32) {
    *(float4*)(outf + row) = make_float4(o0, o1, o2, o3);
  } else {
    us4 r;
    r.v[0] = f2b(o0); r.v[1] = f2b(o1); r.v[2] = f2b(o2); r.v[3] = f2b(o3);
    *(us4*)(h + row) = r;
  }
}

// --------------------------- launch -----------------------------------------

extern "C" void kernel_launch(void* const* d_in, const int* in_sizes, int n_in,
                              void* d_out, int out_size, void* d_ws, size_t ws_size,
                              hipStream_t stream) {
  const float* x     = (const float*)d_in[0];
  const float* graph = (const float*)d_in[1];
  const float* in_w  = (const float*)d_in[2];
  const float* in_b  = (const float*)d_in[3];

  char* ws = (char*)d_ws;
  size_t off = 0;
  auto alloc = [&](size_t bytes) -> void* {
    void* p = ws + off;
    off += (bytes + 255) & ~(size_t)255;
    return p;
  };
  float* dd    = (float*)alloc(2048 * 4);
  float* stats = (float*)alloc(16 * 12 * 2 * 4);
  float* part  = (float*)alloc(16 * 8 * 8 * 2 * 4);
  float* gwT   = (float*)alloc((size_t)64 * 2048 * 4);
  float* gbT   = (float*)alloc((size_t)64 * 2048 * 4);
  u16* wpg  = (u16*)alloc((size_t)1536 * 8 * 2);
  u16* wpt  = (u16*)alloc((size_t)512 * 8 * 2);
  u16* wp2  = (u16*)alloc((size_t)768 * 8 * 2);
  u16* L    = (u16*)alloc((size_t)2048 * 2048 * 2);
  u16* h0   = (u16*)alloc((size_t)16 * 64 * 12 * 2000 * 2);
  u16* Xp   = (u16*)alloc((size_t)5120 * 2048 * 2);
  u16* Y1   = (u16*)alloc((size_t)5120 * 2048 * 2);
  u16* Y2   = (u16*)alloc((size_t)5120 * 2048 * 2);
  u16* h1   = (u16*)alloc((size_t)16 * 64 * 8 * 2000 * 2);
  u16* h2   = h0;  // reuse: h0 dead after block-1 GLU
  if (off > ws_size) return;

  k_deg<<<dim3(2000), dim3(256), 0, stream>>>(graph, dd);
  k_lap<<<dim3(2, 2048), dim3(256), 0, stream>>>(graph, dd, L);
  k_inconv<<<dim3(2, 192), dim3(256), 0, stream>>>(x, in_w, in_b, h0);

  for (int blk = 0; blk < 2; ++blk) {
    const int base = 4 + blk * 10;
    const float* t1w = (const float*)d_in[base + 0];
    const float* t1b = (const float*)d_in[base + 1];
    const float* aw  = (const float*)d_in[base + 2];
    const float* ab  = (const float*)d_in[base + 3];
    const float* th  = (const float*)d_in[base + 4];
    const float* sb  = (const float*)d_in[base + 5];
    const float* t2w = (const float*)d_in[base + 6];
    const float* t2b = (const float*)d_in[base + 7];
    const float* lng = (const float*)d_in[base + 8];
    const float* lnb = (const float*)d_in[base + 9];

    const int T_in = (blk == 0) ? 12 : 8;
    const int T_g  = T_in - 2;  // 10 / 6
    const int T_o  = T_g - 2;   // 8 / 4
    const u16* hin = (blk == 0) ? h0 : h1;
    u16* hout      = (blk == 0) ? h1 : h2;
    const int M = 16 * 32 * T_g;  // 5120 / 3072

    k_wpack<<<dim3(3), dim3(256), 0, stream>>>(t1w, aw, th, t2w, wpg, wpt, wp2);
    k_lngbT<<<dim3(8, 64), dim3(256), 0, stream>>>(lng, lnb, gwT, gbT);
    k_mix<0><<<dim3(32, 16 * T_g), dim3(256), 0, stream>>>(
        hin, wpg, t1b, ab, Xp, T_in, T_g);
    k_gemm<<<dim3(16, M / 128), dim3(256), 0, stream>>>(Xp, L, Y1);
    k_gemm<<<dim3(16, M / 128), dim3(256), 0, stream>>>(Y1, L, Y2);
    k_mix12<<<dim3(32, 16), dim3(256), 0, stream>>>(
        Xp, Y1, Y2, wpt, wp2, sb, t2b, hout, T_g, T_o);
    k_lnpart<<<dim3(16 * T_o, 8), dim3(256), 0, stream>>>(hout, part, T_o);
    k_lnfin<<<dim3(1), dim3(256), 0, stream>>>(part, stats, 16 * T_o);
    k_lnapply<<<dim3(2, 16 * 64 * T_o), dim3(256), 0, stream>>>(
        hout, stats, gwT, gbT, (float*)d_out, T_o, blk);
  }
}

// Round 7
// 548.509 us; speedup vs baseline: 1.0810x; 1.0201x over previous
//
#include <hip/hip_runtime.h>

// ---------------------------------------------------------------------------
// STEncoder (STGCN-style) on MI355X.
// B=16, N=2000 (pad 2048), T=12, D_IN=3, C=64, CM=32, KS=KT=3.
// Chebyshev: T0=I, T2=2L^2-I -> 2 big GEMMs/block, k0/k2 folded into theta.
// R7: k_gemm triple-buffer pipeline (AITER-style): per-iter s_waitcnt
//     vmcnt(4) -- never drain to 0 -- raw s_barrier, DMA tile i+2 while
//     computing tile i. 48KB LDS, 3 blocks/CU, grid fully resident.
// ---------------------------------------------------------------------------

typedef unsigned short u16;
typedef __attribute__((ext_vector_type(8))) short short8;   // 8 x bf16 frag
typedef __attribute__((ext_vector_type(4))) float floatx4;  // MFMA acc

struct __attribute__((aligned(8))) us4 { u16 v[4]; };

#define AS1 __attribute__((address_space(1)))
#define AS3 __attribute__((address_space(3)))

__device__ __forceinline__ float b2f(u16 h) {
  union { unsigned int u; float f; } v;
  v.u = ((unsigned int)h) << 16;
  return v.f;
}
__device__ __forceinline__ u16 f2b(float f) {
  union { float f; unsigned int u; } v;
  v.f = f;
  unsigned int r = (v.u + 0x7fffu + ((v.u >> 16) & 1u)) >> 16;
  return (u16)r;
}
__device__ __forceinline__ void gl_lds16(const u16* g, u16* l) {
  __builtin_amdgcn_global_load_lds((const AS1 unsigned int*)g,
                                   (AS3 unsigned int*)l, 16, 0, 0);
}
__device__ __forceinline__ us4 load4_guard(const u16* gp, int n) {
  if (n + 3 < 2000) return *(const us4*)gp;
  us4 r;
#pragma unroll
  for (int i = 0; i < 4; ++i) r.v[i] = (n + i < 2000) ? gp[i] : (u16)0;
  return r;
}

// --------------------------- graph preprocessing ---------------------------

__global__ void k_deg(const float* __restrict__ graph, float* __restrict__ d) {
  const int n = blockIdx.x;
  const int tid = threadIdx.x;
  float s = 0.f;
  const float* row = graph + (size_t)n * 2000;
  for (int m4 = tid; m4 < 500; m4 += 256) {
    const float4 g = *(const float4*)(row + m4 * 4);
    s += (g.x + g.y) + (g.z + g.w);
  }
  __shared__ float red[256];
  red[tid] = s;
  __syncthreads();
  for (int st = 128; st > 0; st >>= 1) {
    if (tid < st) red[tid] += red[tid + st];
    __syncthreads();
  }
  if (tid == 0) d[n] = rsqrtf(fmaxf(red[0] + 1.f, 1e-6f));
}

__global__ void k_lap(const float* __restrict__ graph, const float* __restrict__ d,
                      u16* __restrict__ L) {
  const int m = blockIdx.x * 1024 + threadIdx.x * 4;
  const int n = blockIdx.y;
  us4 r = {{0, 0, 0, 0}};
  if (n < 2000 && m < 2000) {
    const float4 g4 = *(const float4*)(graph + (size_t)n * 2000 + m);
    const float4 d4 = *(const float4*)(d + m);
    const float dn = d[n];
    const float gv[4] = {g4.x, g4.y, g4.z, g4.w};
    const float dv[4] = {d4.x, d4.y, d4.z, d4.w};
#pragma unroll
    for (int i = 0; i < 4; ++i) {
      const float delta = (n == m + i) ? 1.f : 0.f;
      r.v[i] = f2b(delta - dn * (gv[i] + delta) * dv[i]);
    }
  }
  *(us4*)(L + (size_t)n * 2048 + m) = r;
}

// --------------------------- input 1x1 conv (K=3) ---------------------------

__global__ void k_inconv(const float* __restrict__ x, const float* __restrict__ w,
                         const float* __restrict__ bias, u16* __restrict__ h0) {
  const int n = blockIdx.x * 1024 + threadIdx.x * 4;
  if (n >= 2000) return;
  const int b = blockIdx.y / 12, t = blockIdx.y % 12;
  const float4 x0 = *(const float4*)(x + ((size_t)(b * 3 + 0) * 12 + t) * 2000 + n);
  const float4 x1 = *(const float4*)(x + ((size_t)(b * 3 + 1) * 12 + t) * 2000 + n);
  const float4 x2 = *(const float4*)(x + ((size_t)(b * 3 + 2) * 12 + t) * 2000 + n);
  for (int o = 0; o < 64; ++o) {
    const float w0 = w[o], w1 = w[64 + o], w2 = w[128 + o], bb = bias[o];
    us4 r;
    r.v[0] = f2b(x0.x * w0 + x1.x * w1 + x2.x * w2 + bb);
    r.v[1] = f2b(x0.y * w0 + x1.y * w1 + x2.y * w2 + bb);
    r.v[2] = f2b(x0.z * w0 + x1.z * w1 + x2.z * w2 + bb);
    r.v[3] = f2b(x0.w * w0 + x1.w * w1 + x2.w * w2 + bb);
    *(us4*)(h0 + ((size_t)(b * 64 + o) * 12 + t) * 2000 + n) = r;
  }
}

// --------------------------- weight fragment packing ------------------------
__global__ void k_wpack(const float* __restrict__ t1w, const float* __restrict__ aw,
                        const float* __restrict__ th, const float* __restrict__ t2w,
                        u16* __restrict__ wglu, u16* __restrict__ wth,
                        u16* __restrict__ wt2) {
  const int mode = blockIdx.x;
  const int tid = threadIdx.x;
  if (mode == 0) {  // GLU: M=64, K=192, KS=6
    for (int idx = tid; idx < 1536 * 8; idx += 256) {
      int chunk = idx >> 3, j = idx & 7;
      int l15 = chunk & 15, quad = (chunk >> 4) & 3, g = chunk >> 6;
      int ks = g % 6, mi = g / 6;
      int o = mi * 16 + l15;
      int k = ks * 32 + quad * 8 + j;
      int c = k & 63, dt = k >> 6;
      float v = t1w[(o * 64 + c) * 3 + dt];
      if (o < 32 && dt == 2) v += aw[o * 64 + c];
      wglu[idx] = f2b(v);
    }
  } else if (mode == 1) {  // theta: M=32, K=96, KS=3 (padded to 512 chunks)
    for (int idx = tid; idx < 512 * 8; idx += 256) {
      int chunk = idx >> 3, j = idx & 7;
      int l15 = chunk & 15, quad = (chunk >> 4) & 3, g = chunk >> 6;
      float v = 0.f;
      if (g < 6) {
        int ks = g % 3, mi = g / 3;
        int o = mi * 16 + l15;
        int k = ks * 32 + quad * 8 + j;
        int i = k & 31, src = k >> 5;
        const float* p = th + (i * 32 + o) * 3;
        v = (src == 0) ? (p[0] - p[2]) : (src == 1 ? p[1] : 2.f * p[2]);
      }
      wth[idx] = f2b(v);
    }
  } else {  // t2: M=64, K=96, KS=3
    for (int idx = tid; idx < 768 * 8; idx += 256) {
      int chunk = idx >> 3, j = idx & 7;
      int l15 = chunk & 15, quad = (chunk >> 4) & 3, g = chunk >> 6;
      int ks = g % 3, mi = g / 3;
      int o = mi * 16 + l15;
      int k = ks * 32 + quad * 8 + j;
      int i = k & 31, dt = k >> 5;
      wt2[idx] = f2b(t2w[(o * 32 + i) * 3 + dt]);
    }
  }
}

// --------------------------- GLU MFMA kernel (mode 0 only) ------------------
template <int MODE>
__global__ __launch_bounds__(256, 3)
void k_mix(const u16* __restrict__ x0, const u16* __restrict__ wp,
           const float* __restrict__ b0, const float* __restrict__ b1,
           u16* __restrict__ out, int T_in, int T) {
  constexpr int K = 192;
  constexpr int KS = K / 32;
  constexpr int MT = 4;
  constexpr int NT = 64;
  constexpr int NBLK = NT / 16;
  constexpr int TPR = NT / 4;
  constexpr int GPP = 256 / TPR;
  constexpr int WCH = ((MT * KS * 64) + 255) & ~255;
  constexpr int XCH = KS * NBLK * 65;
  __shared__ __align__(16) u16 lw[WCH * 8];
  __shared__ __align__(16) u16 lx[XCH * 8];

  const int tid = threadIdx.x;
  const int lane = tid & 63, wave = tid >> 6;
  const int quad = lane >> 4, l15 = lane & 15;
  const int n0 = blockIdx.x * NT;
  const int b = blockIdx.y / T, t = blockIdx.y % T;

#pragma unroll
  for (int p = 0; p < WCH / 256; ++p)
    gl_lds16(wp + (size_t)(p * 256 + wave * 64 + lane) * 8,
             &lw[(p * 256 + wave * 64) * 8]);

  const bool guard = (n0 + NT > 2000);
  const int nloc = (tid % TPR) * 4;
  us4 rv[3][4];
#pragma unroll
  for (int p = 0; p < 3; ++p) {
    const int k4 = p * GPP + (tid / TPR);
#pragma unroll
    for (int i = 0; i < 4; ++i) {
      const int k = k4 * 4 + i;
      const u16* rp =
          x0 + (size_t)((b * 64 + (k & 63)) * T_in + t + (k >> 6)) * 2000;
      rv[p][i] = guard ? load4_guard(rp + n0 + nloc, n0 + nloc)
                       : *(const us4*)(rp + n0 + nloc);
    }
  }
#pragma unroll
  for (int p = 0; p < 3; ++p) {
    const int k4 = p * GPP + (tid / TPR);
    const int ks = k4 >> 3, q8 = k4 & 7;
    const int quadw = (q8 >> 1) & 3;
    const int j0 = (q8 & 1) * 4;
#pragma unroll
    for (int i = 0; i < 4; ++i) {
      const int nn = nloc + i;
      const int chunk = (ks * NBLK + (nn >> 4)) * 65 + quadw * 16 + (nn & 15);
      us4 wv;
      wv.v[0] = rv[p][0].v[i]; wv.v[1] = rv[p][1].v[i];
      wv.v[2] = rv[p][2].v[i]; wv.v[3] = rv[p][3].v[i];
      *(us4*)&lx[chunk * 8 + j0] = wv;
    }
  }
  asm volatile("s_waitcnt vmcnt(0)" ::: "memory");
  __syncthreads();

  floatx4 acc[MT] = {};
#pragma unroll
  for (int ks = 0; ks < KS; ++ks) {
    short8 bfr = *(const short8*)&lx[(((ks * NBLK + wave) * 65) + lane) * 8];
#pragma unroll
    for (int mi = 0; mi < MT; ++mi) {
      short8 afr = *(const short8*)&lw[((mi * KS + ks) * 64 + lane) * 8];
      acc[mi] = __builtin_amdgcn_mfma_f32_16x16x32_bf16(afr, bfr, acc[mi], 0, 0, 0);
    }
  }

  const int n = n0 + wave * 16 + l15;
#pragma unroll
  for (int mi = 0; mi < 2; ++mi)
#pragma unroll
    for (int r = 0; r < 4; ++r) {
      const int i = mi * 16 + quad * 4 + r;
      const float sv = acc[mi][r] + b0[i] + b1[i];
      const float gt = acc[mi + 2][r] + b0[32 + i];
      const float val = sv / (1.f + __expf(-gt));
      out[(size_t)((b * 32 + i) * T + t) * 2048 + n] = f2b(val);
    }
}

// --------------------------- fused theta + t2 kernel ------------------------
__global__ __launch_bounds__(256, 2)
void k_mix12(const u16* __restrict__ x0, const u16* __restrict__ y1,
             const u16* __restrict__ y2, const u16* __restrict__ wth,
             const u16* __restrict__ wt2, const float* __restrict__ sb,
             const float* __restrict__ t2b, u16* __restrict__ out,
             int T_g, int T_o) {
  __shared__ __align__(16) u16 lw1[512 * 8];        //  8 KB theta A-frags
  __shared__ __align__(16) u16 lw2[768 * 8];        // 12 KB t2 A-frags
  __shared__ __align__(16) u16 lx[780 * 8];         // 12 KB staging (96x64)
  __shared__ __align__(16) u16 lt[10 * 260 * 8];    // 41 KB theta-out ring

  const int tid = threadIdx.x;
  const int lane = tid & 63, wave = tid >> 6;
  const int quad = lane >> 4, l15 = lane & 15;
  const int n0 = blockIdx.x * 64;
  const int b = blockIdx.y;
  const int n = n0 + wave * 16 + l15;

#pragma unroll
  for (int p = 0; p < 2; ++p)
    gl_lds16(wth + (size_t)(p * 256 + wave * 64 + lane) * 8,
             &lw1[(p * 256 + wave * 64) * 8]);
#pragma unroll
  for (int p = 0; p < 3; ++p)
    gl_lds16(wt2 + (size_t)(p * 256 + wave * 64 + lane) * 8,
             &lw2[(p * 256 + wave * 64) * 8]);

  const int nloc = (tid & 15) * 4;      // TPR=16
  const int g16 = tid >> 4;             // 0..15 row-groups per pass

  for (int t = 0; t < T_g; ++t) {
    __syncthreads();  // lx free (prev theta done), lw DMAs drained (1st iter)
    us4 rv[2][4];
#pragma unroll
    for (int p = 0; p < 2; ++p) {
      const int k4 = p * 16 + g16;
      if (k4 < 24) {
#pragma unroll
        for (int i = 0; i < 4; ++i) {
          const int k = k4 * 4 + i;
          const u16* base = (k < 32) ? x0 : ((k < 64) ? y1 : y2);
          rv[p][i] = *(const us4*)(base +
              (size_t)((b * 32 + (k & 31)) * T_g + t) * 2048 + n0 + nloc);
        }
      }
    }
#pragma unroll
    for (int p = 0; p < 2; ++p) {
      const int k4 = p * 16 + g16;
      if (k4 < 24) {
        const int ks = k4 >> 3, q8 = k4 & 7;
        const int quadw = (q8 >> 1) & 3;
        const int j0 = (q8 & 1) * 4;
#pragma unroll
        for (int i = 0; i < 4; ++i) {
          const int nn = nloc + i;
          const int chunk = (ks * 4 + (nn >> 4)) * 65 + quadw * 16 + (nn & 15);
          us4 wv;
          wv.v[0] = rv[p][0].v[i]; wv.v[1] = rv[p][1].v[i];
          wv.v[2] = rv[p][2].v[i]; wv.v[3] = rv[p][3].v[i];
          *(us4*)&lx[chunk * 8 + j0] = wv;
        }
      }
    }
    __syncthreads();

    floatx4 acc[2] = {};
#pragma unroll
    for (int ks = 0; ks < 3; ++ks) {
      short8 bfr = *(const short8*)&lx[((ks * 4 + wave) * 65 + lane) * 8];
#pragma unroll
      for (int mi = 0; mi < 2; ++mi) {
        short8 afr = *(const short8*)&lw1[((mi * 3 + ks) * 64 + lane) * 8];
        acc[mi] = __builtin_amdgcn_mfma_f32_16x16x32_bf16(afr, bfr, acc[mi], 0, 0, 0);
      }
    }
#pragma unroll
    for (int mi = 0; mi < 2; ++mi)
#pragma unroll
      for (int r = 0; r < 4; ++r) {
        const int o = mi * 16 + quad * 4 + r;
        const float v = acc[mi][r] + sb[o] +
            b2f(lx[(wave * 65 + ((o >> 3) & 3) * 16 + l15) * 8 + (o & 7)]);
        lt[((t * 4 + wave) * 65 + ((o >> 3) & 3) * 16 + l15) * 8 + (o & 7)] =
            f2b(fmaxf(v, 0.f));
      }
  }
  __syncthreads();

  for (int to = 0; to < T_o; ++to) {
    floatx4 acc[4] = {};
#pragma unroll
    for (int ks = 0; ks < 3; ++ks) {
      short8 bfr = *(const short8*)&lt[(((to + ks) * 4 + wave) * 65 + lane) * 8];
#pragma unroll
      for (int mi = 0; mi < 4; ++mi) {
        short8 afr = *(const short8*)&lw2[((mi * 3 + ks) * 64 + lane) * 8];
        acc[mi] = __builtin_amdgcn_mfma_f32_16x16x32_bf16(afr, bfr, acc[mi], 0, 0, 0);
      }
    }
    if (n < 2000) {
#pragma unroll
      for (int mi = 0; mi < 4; ++mi)
#pragma unroll
        for (int r = 0; r < 4; ++r) {
          const int o = mi * 16 + quad * 4 + r;
          float v = acc[mi][r] + t2b[o];
          if (o < 32)
            v += b2f(lt[(((to + 2) * 4 + wave) * 65 +
                         ((o >> 3) & 3) * 16 + l15) * 8 + (o & 7)]);
          out[(size_t)((b * 64 + o) * T_o + to) * 2000 + n] = f2b(fmaxf(v, 0.f));
        }
    }
  }
}

// --------------------------- bf16 MFMA GEMM (C = A * Bt^T) ------------------
// 256 threads, 128x128 block tile, 2x2 waves of 64x64; sigma-swizzled LDS.
// R7: TRIPLE-buffer software pipeline. Per iteration:
//   s_waitcnt vmcnt(4)  (retire tile i's 4 DMAs; tile i+1 stays in flight)
//   s_barrier           (all waves: tile i landed, tile i-1 reads retired)
//   DMA tile i+2 -> free buffer ; ds_read + 16 MFMA on tile i.
// Each tile gets 2 iterations of load latency slack (vmcnt never drains to 0
// except the peeled last tile). 48KB LDS -> 3 blocks/CU, grid fully resident.
__global__ __launch_bounds__(256, 3)
void k_gemm(const u16* __restrict__ A, const u16* __restrict__ Bt,
            u16* __restrict__ C) {
  constexpr int K = 2048;
  constexpr int NTI = K / 32;  // 64 k-tiles
  __shared__ u16 As[3][128 * 32];
  __shared__ u16 Bs[3][128 * 32];
  const int tid = threadIdx.x;
  const int lane = tid & 63, wave = tid >> 6;
  const int m0 = blockIdx.y * 128, n0 = blockIdx.x * 128;
  const int wy = wave >> 1, wx = wave & 1;
  const int quad = lane >> 4, l15 = lane & 15;

  const int c0 = wave * 128 + lane;
  const int c1 = c0 + 64;
  const int r0 = c0 >> 2, r1 = c1 >> 2;
  const int q0 = (((c0 & 3) - ((r0 & 15) + ((r0 & 15) >> 2))) & 3);
  const int q1 = (((c1 & 3) - ((r1 & 15) + ((r1 & 15) >> 2))) & 3);
  const u16* Ag0 = A + (size_t)(m0 + r0) * K + q0 * 8;
  const u16* Ag1 = A + (size_t)(m0 + r1) * K + q1 * 8;
  const u16* Bg0 = Bt + (size_t)(n0 + r0) * K + q0 * 8;
  const u16* Bg1 = Bt + (size_t)(n0 + r1) * K + q1 * 8;
  const int lofs0 = (wave * 2 + 0) * 512;
  const int lofs1 = (wave * 2 + 1) * 512;

  const int sigr = (l15 + (l15 >> 2)) & 3;
  const int cofs = ((quad + sigr) & 3) * 8;

  floatx4 acc[4][4] = {};

  auto stage = [&](int tile, int buf) {
    const int kn = tile * 32;
    gl_lds16(Ag0 + kn, As[buf] + lofs0);
    gl_lds16(Ag1 + kn, As[buf] + lofs1);
    gl_lds16(Bg0 + kn, Bs[buf] + lofs0);
    gl_lds16(Bg1 + kn, Bs[buf] + lofs1);
  };
  auto compute = [&](int buf) {
    const u16* as = As[buf];
    const u16* bs = Bs[buf];
    short8 af[4], bf[4];
#pragma unroll
    for (int mi = 0; mi < 4; ++mi)
      af[mi] = *(const short8*)&as[(wy * 64 + mi * 16 + l15) * 32 + cofs];
#pragma unroll
    for (int ni = 0; ni < 4; ++ni)
      bf[ni] = *(const short8*)&bs[(wx * 64 + ni * 16 + l15) * 32 + cofs];
#pragma unroll
    for (int mi = 0; mi < 4; ++mi)
#pragma unroll
      for (int ni = 0; ni < 4; ++ni)
        acc[mi][ni] = __builtin_amdgcn_mfma_f32_16x16x32_bf16(
            af[mi], bf[ni], acc[mi][ni], 0, 0, 0);
  };

  stage(0, 0);
  stage(1, 1);

  int cur = 0, nxt = 1, fre = 2;
  for (int it = 0; it < NTI - 1; ++it) {
    asm volatile("s_waitcnt vmcnt(4)" ::: "memory");  // tile it landed
    asm volatile("s_barrier" ::: "memory");
    if (it + 2 < NTI) stage(it + 2, fre);
    compute(cur);
    const int t = cur; cur = nxt; nxt = fre; fre = t;
  }
  asm volatile("s_waitcnt vmcnt(0)" ::: "memory");    // peeled last tile
  asm volatile("s_barrier" ::: "memory");
  compute(cur);

#pragma unroll
  for (int mi = 0; mi < 4; ++mi) {
#pragma unroll
    for (int ni = 0; ni < 4; ++ni) {
      const int row = m0 + wy * 64 + mi * 16 + quad * 4;
      const int col = n0 + wx * 64 + ni * 16 + l15;
#pragma unroll
      for (int r = 0; r < 4; ++r)
        C[(size_t)(row + r) * K + col] = f2b(acc[mi][ni][r]);
    }
  }
}

// --------------------------- LayerNorm --------------------------------------

__global__ void k_lnpart(const u16* __restrict__ h, float* __restrict__ part, int T) {
  const int bt = blockIdx.x, cg = blockIdx.y;
  const int b = bt / T, t = bt % T;
  const int tid = threadIdx.x;
  float s = 0.f, ss = 0.f;
  for (int c = cg * 8; c < cg * 8 + 8; ++c) {
    const u16* row = h + (size_t)((b * 64 + c) * T + t) * 2000;
    for (int n = tid * 4; n < 2000; n += 1024) {
      const us4 hv = *(const us4*)(row + n);
#pragma unroll
      for (int i = 0; i < 4; ++i) {
        const float v = b2f(hv.v[i]);
        s += v; ss += v * v;
      }
    }
  }
  __shared__ float r1[256], r2[256];
  r1[tid] = s; r2[tid] = ss;
  __syncthreads();
  for (int st = 128; st > 0; st >>= 1) {
    if (tid < st) { r1[tid] += r1[tid + st]; r2[tid] += r2[tid + st]; }
    __syncthreads();
  }
  if (tid == 0) {
    part[(bt * 8 + cg) * 2 + 0] = r1[0];
    part[(bt * 8 + cg) * 2 + 1] = r2[0];
  }
}

__global__ void k_lnfin(const float* __restrict__ part, float* __restrict__ stats,
                        int BT) {
  const int i = blockIdx.x * 256 + threadIdx.x;
  if (i >= BT) return;
  float s = 0.f, ss = 0.f;
  for (int g = 0; g < 8; ++g) {
    s  += part[(i * 8 + g) * 2 + 0];
    ss += part[(i * 8 + g) * 2 + 1];
  }
  const float inv = 1.f / 128000.f;
  const float mu = s * inv;
  const float var = ss * inv - mu * mu;
  stats[i * 2] = mu;
  stats[i * 2 + 1] = rsqrtf(var + 1e-5f);
}

// transpose gamma/beta [2000,64] -> [64,2048] (pad zeros)
__global__ void k_lngbT(const float* __restrict__ gw, const float* __restrict__ gb,
                        float* __restrict__ gwT, float* __restrict__ gbT) {
  const int n = blockIdx.x * 256 + threadIdx.x;
  const int c = blockIdx.y;
  float vw = 0.f, vb = 0.f;
  if (n < 2000) {
    vw = gw[(size_t)n * 64 + c];
    vb = gb[(size_t)n * 64 + c];
  }
  gwT[(size_t)c * 2048 + n] = vw;
  gbT[(size_t)c * 2048 + n] = vb;
}

__global__ void k_lnapply(u16* __restrict__ h, const float* __restrict__ stats,
                          const float* __restrict__ gwT, const float* __restrict__ gbT,
                          float* __restrict__ outf, int T, int write_f32) {
  const int n = blockIdx.x * 1024 + threadIdx.x * 4;
  if (n >= 2000) return;
  int by = blockIdx.y;
  const int t = by % T; by /= T;
  const int c = by & 63;
  const int b = by >> 6;
  const int bt = b * T + t;
  const float mu = stats[bt * 2], rs = stats[bt * 2 + 1];
  const size_t row = (size_t)((b * 64 + c) * T + t) * 2000 + n;
  const us4 hv = *(const us4*)(h + row);
  const float4 w4 = *(const float4*)(gwT + (size_t)c * 2048 + n);
  const float4 b4 = *(const float4*)(gbT + (size_t)c * 2048 + n);
  const float o0 = (b2f(hv.v[0]) - mu) * rs * w4.x + b4.x;
  const float o1 = (b2f(hv.v[1]) - mu) * rs * w4.y + b4.y;
  const float o2 = (b2f(hv.v[2]) - mu) * rs * w4.z + b4.z;
  const float o3 = (b2f(hv.v[3]) - mu) * rs * w4.w + b4.w;
  if (write_f32) {
    *(float4*)(outf + row) = make_float4(o0, o1, o2, o3);
  } else {
    us4 r;
    r.v[0] = f2b(o0); r.v[1] = f2b(o1); r.v[2] = f2b(o2); r.v[3] = f2b(o3);
    *(us4*)(h + row) = r;
  }
}

// --------------------------- launch -----------------------------------------

extern "C" void kernel_launch(void* const* d_in, const int* in_sizes, int n_in,
                              void* d_out, int out_size, void* d_ws, size_t ws_size,
                              hipStream_t stream) {
  const float* x     = (const float*)d_in[0];
  const float* graph = (const float*)d_in[1];
  const float* in_w  = (const float*)d_in[2];
  const float* in_b  = (const float*)d_in[3];

  char* ws = (char*)d_ws;
  size_t off = 0;
  auto alloc = [&](size_t bytes) -> void* {
    void* p = ws + off;
    off += (bytes + 255) & ~(size_t)255;
    return p;
  };
  float* dd    = (float*)alloc(2048 * 4);
  float* stats = (float*)alloc(16 * 12 * 2 * 4);
  float* part  = (float*)alloc(16 * 8 * 8 * 2 * 4);
  float* gwT   = (float*)alloc((size_t)64 * 2048 * 4);
  float* gbT   = (float*)alloc((size_t)64 * 2048 * 4);
  u16* wpg  = (u16*)alloc((size_t)1536 * 8 * 2);
  u16* wpt  = (u16*)alloc((size_t)512 * 8 * 2);
  u16* wp2  = (u16*)alloc((size_t)768 * 8 * 2);
  u16* L    = (u16*)alloc((size_t)2048 * 2048 * 2);
  u16* h0   = (u16*)alloc((size_t)16 * 64 * 12 * 2000 * 2);
  u16* Xp   = (u16*)alloc((size_t)5120 * 2048 * 2);
  u16* Y1   = (u16*)alloc((size_t)5120 * 2048 * 2);
  u16* Y2   = (u16*)alloc((size_t)5120 * 2048 * 2);
  u16* h1   = (u16*)alloc((size_t)16 * 64 * 8 * 2000 * 2);
  u16* h2   = h0;  // reuse: h0 dead after block-1 GLU
  if (off > ws_size) return;

  k_deg<<<dim3(2000), dim3(256), 0, stream>>>(graph, dd);
  k_lap<<<dim3(2, 2048), dim3(256), 0, stream>>>(graph, dd, L);
  k_inconv<<<dim3(2, 192), dim3(256), 0, stream>>>(x, in_w, in_b, h0);

  for (int blk = 0; blk < 2; ++blk) {
    const int base = 4 + blk * 10;
    const float* t1w = (const float*)d_in[base + 0];
    const float* t1b = (const float*)d_in[base + 1];
    const float* aw  = (const float*)d_in[base + 2];
    const float* ab  = (const float*)d_in[base + 3];
    const float* th  = (const float*)d_in[base + 4];
    const float* sb  = (const float*)d_in[base + 5];
    const float* t2w = (const float*)d_in[base + 6];
    const float* t2b = (const float*)d_in[base + 7];
    const float* lng = (const float*)d_in[base + 8];
    const float* lnb = (const float*)d_in[base + 9];

    const int T_in = (blk == 0) ? 12 : 8;
    const int T_g  = T_in - 2;  // 10 / 6
    const int T_o  = T_g - 2;   // 8 / 4
    const u16* hin = (blk == 0) ? h0 : h1;
    u16* hout      = (blk == 0) ? h1 : h2;
    const int M = 16 * 32 * T_g;  // 5120 / 3072

    k_wpack<<<dim3(3), dim3(256), 0, stream>>>(t1w, aw, th, t2w, wpg, wpt, wp2);
    k_lngbT<<<dim3(8, 64), dim3(256), 0, stream>>>(lng, lnb, gwT, gbT);
    k_mix<0><<<dim3(32, 16 * T_g), dim3(256), 0, stream>>>(
        hin, wpg, t1b, ab, Xp, T_in, T_g);
    k_gemm<<<dim3(16, M / 128), dim3(256), 0, stream>>>(Xp, L, Y1);
    k_gemm<<<dim3(16, M / 128), dim3(256), 0, stream>>>(Y1, L, Y2);
    k_mix12<<<dim3(32, 16), dim3(256), 0, stream>>>(
        Xp, Y1, Y2, wpt, wp2, sb, t2b, hout, T_g, T_o);
    k_lnpart<<<dim3(16 * T_o, 8), dim3(256), 0, stream>>>(hout, part, T_o);
    k_lnfin<<<dim3(1), dim3(256), 0, stream>>>(part, stats, 16 * T_o);
    k_lnapply<<<dim3(2, 16 * 64 * T_o), dim3(256), 0, stream>>>(
        hout, stats, gwT, gbT, (float*)d_out, T_o, blk);
  }
}